// Round 8
// baseline (324.567 us; speedup 1.0000x reference)
//
#include <hip/hip_runtime.h>

typedef __attribute__((ext_vector_type(8))) __bf16 bf16x8;
typedef __attribute__((ext_vector_type(4))) __bf16 bf16x4;
typedef __attribute__((ext_vector_type(4))) float f32x4;
typedef __attribute__((ext_vector_type(16))) float f32x16;

#define SCALE_LOG2E 0.18033688011112042f  // 0.125 * log2(e)

__device__ __forceinline__ f32x4 mfma16(bf16x8 a, bf16x8 b, f32x4 c) {
  return __builtin_amdgcn_mfma_f32_16x16x32_bf16(a, b, c, 0, 0, 0);
}
__device__ __forceinline__ f32x16 mfma32(bf16x8 a, bf16x8 b, f32x16 c) {
  return __builtin_amdgcn_mfma_f32_32x32x16_bf16(a, b, c, 0, 0, 0);
}

__device__ __forceinline__ void gload_lds16(const void* g, void* l) {
  __builtin_amdgcn_global_load_lds(
      (__attribute__((address_space(1))) void*)(void*)g,
      (__attribute__((address_space(3))) void*)l, 16, 0, 0);
}

// read swizzled [row][64-elem] LDS tile: logical chunk lc (0..7) of row
__device__ __forceinline__ bf16x8 ldsfrag(const __bf16* base, int row, int lc) {
  return *(const bf16x8*)(base + row * 64 + ((lc ^ (row & 7)) << 3));
}

// ---------------- cast kernels ----------------

__global__ __launch_bounds__(256) void cast_plain(const float* __restrict__ in,
                                                  __bf16* __restrict__ out) {
  size_t t = (size_t)blockIdx.x * 256 + threadIdx.x;
  const float4* p = (const float4*)(in + t * 8);
  float4 a = p[0], b = p[1];
  bf16x8 v;
  v[0] = (__bf16)a.x; v[1] = (__bf16)a.y; v[2] = (__bf16)a.z; v[3] = (__bf16)a.w;
  v[4] = (__bf16)b.x; v[5] = (__bf16)b.y; v[6] = (__bf16)b.z; v[7] = (__bf16)b.w;
  *(bf16x8*)(out + t * 8) = v;
}

__global__ __launch_bounds__(256) void cast_cat(const float* __restrict__ mem,
                                                const float* __restrict__ w,
                                                __bf16* __restrict__ out) {
  size_t t = (size_t)blockIdx.x * 256 + threadIdx.x;
  size_t o = t * 8;
  int c = (int)(o & 1023);
  int row = (int)(o >> 10);
  int tt = row & 2047;
  int b = row >> 11;
  const float* src = (tt < 1024)
      ? (mem + ((size_t)(b * 1024 + tt) * 1024 + c))
      : (w + ((size_t)(b * 1024 + (tt - 1024)) * 1024 + c));
  float4 a = ((const float4*)src)[0], d = ((const float4*)src)[1];
  bf16x8 v;
  v[0] = (__bf16)a.x; v[1] = (__bf16)a.y; v[2] = (__bf16)a.z; v[3] = (__bf16)a.w;
  v[4] = (__bf16)d.x; v[5] = (__bf16)d.y; v[6] = (__bf16)d.z; v[7] = (__bf16)d.w;
  *(bf16x8*)(out + o) = v;
}

// ---------------- GEMM: C = A(MxK) * B(NxK)^T ----------------
template <int MODE>
__global__ __launch_bounds__(256, 2) void gemm_bt(const __bf16* __restrict__ A,
                                                  const __bf16* __restrict__ B,
                                                  __bf16* __restrict__ Cb,
                                                  float* __restrict__ Cf,
                                                  const float* __restrict__ Res,
                                                  int M, int N, int K, int skipq) {
  if (skipq && blockIdx.x < 8 && (blockIdx.y & 15) < 8) return;
  __shared__ __bf16 As[128 * 32];
  __shared__ __bf16 Bs[128 * 32];
  const int tid = threadIdx.x;
  const int wid = tid >> 6, lane = tid & 63;
  const int l15 = lane & 15, lhi = lane >> 4;
  const int wr = wid >> 1, wc = wid & 1;
  const size_t arow0 = (size_t)blockIdx.y * 128;
  const size_t brow0 = (size_t)blockIdx.x * 128;

  f32x4 acc[4][4] = {};

  const int c0 = tid, c1 = tid + 256;
  const int r0 = c0 >> 2, o0 = (c0 & 3) * 8;
  const int r1 = c1 >> 2, o1 = (c1 & 3) * 8;
  const __bf16* ga0 = A + (arow0 + r0) * K + o0;
  const __bf16* ga1 = A + (arow0 + r1) * K + o1;
  const __bf16* gb0 = B + (brow0 + r0) * K + o0;
  const __bf16* gb1 = B + (brow0 + r1) * K + o1;
  __bf16* la0 = As + wid * 512;
  __bf16* la1 = As + 2048 + wid * 512;
  __bf16* lb0 = Bs + wid * 512;
  __bf16* lb1 = Bs + 2048 + wid * 512;

  for (int k0 = 0; k0 < K; k0 += 32) {
    gload_lds16(ga0 + k0, la0);
    gload_lds16(ga1 + k0, la1);
    gload_lds16(gb0 + k0, lb0);
    gload_lds16(gb1 + k0, lb1);
    __syncthreads();
    bf16x8 af[4], bf[4];
#pragma unroll
    for (int m = 0; m < 4; ++m)
      af[m] = *(const bf16x8*)(As + (wr * 64 + m * 16 + l15) * 32 + lhi * 8);
#pragma unroll
    for (int n = 0; n < 4; ++n)
      bf[n] = *(const bf16x8*)(Bs + (wc * 64 + n * 16 + l15) * 32 + lhi * 8);
#pragma unroll
    for (int m = 0; m < 4; ++m)
#pragma unroll
      for (int n = 0; n < 4; ++n)
        acc[m][n] = mfma16(af[m], bf[n], acc[m][n]);
    __syncthreads();
  }

#pragma unroll
  for (int m = 0; m < 4; ++m)
#pragma unroll
    for (int n = 0; n < 4; ++n) {
      size_t row = arow0 + wr * 64 + m * 16 + lhi * 4;
      size_t col = brow0 + wc * 64 + n * 16 + l15;
#pragma unroll
      for (int j = 0; j < 4; ++j) {
        size_t idx = (row + j) * (size_t)N + col;
        float v = acc[m][n][j];
        if (MODE == 0) Cb[idx] = (__bf16)v;
        else Cf[idx] = v + Res[idx];
      }
    }
}

// ---------------- V transpose: vT[b][h][d][j] ----------------
__global__ __launch_bounds__(256) void vtrans_kernel(const __bf16* __restrict__ heads,
                                                     __bf16* __restrict__ vT) {
  __shared__ __bf16 T[64][66];
  const int j0 = blockIdx.x * 64;
  const int h = blockIdx.y, b = blockIdx.z;
  const int tid = threadIdx.x;
  {
    int jj = tid >> 2, dq = tid & 3;
    const __bf16* src = heads + ((size_t)(b * 2048 + j0 + jj)) * 3072 + 2048 + h * 64 + dq * 16;
    bf16x8 a = *(const bf16x8*)src;
    bf16x8 c = *(const bf16x8*)(src + 8);
#pragma unroll
    for (int e = 0; e < 8; ++e) { T[jj][dq * 16 + e] = a[e]; T[jj][dq * 16 + 8 + e] = c[e]; }
  }
  __syncthreads();
  {
    int d = tid >> 2, jq = tid & 3;
    bf16x8 o0, o1;
#pragma unroll
    for (int e = 0; e < 8; ++e) { o0[e] = T[jq * 16 + e][d]; o1[e] = T[jq * 16 + 8 + e][d]; }
    __bf16* dst = vT + ((size_t)((b * 16 + h) * 64 + d)) * 2048 + j0 + jq * 16;
    *(bf16x8*)dst = o0;
    *(bf16x8*)(dst + 8) = o1;
  }
}

// ---------------- bias-dot precomputes (scale = 0.125*log2e folded in) ----------------
__global__ __launch_bounds__(256) void ackb_kernel(const __bf16* __restrict__ heads,
                                                   const float* __restrict__ r_w_bias,
                                                   float* __restrict__ ackb) {
  int gid = blockIdx.x * 256 + threadIdx.x;  // 131072
  int j = gid & 2047, bh = gid >> 11, b = bh >> 4, h = bh & 15;
  const __bf16* kp = heads + ((size_t)(b * 2048 + j)) * 3072 + 1024 + h * 64;
  const float* bw = r_w_bias + h * 64;
  float s = 0.f;
#pragma unroll
  for (int o = 0; o < 8; ++o) {
    bf16x8 kv = *(const bf16x8*)(kp + o * 8);
#pragma unroll
    for (int e = 0; e < 8; ++e) s += (float)kv[e] * bw[o * 8 + e];
  }
  ackb[(size_t)bh * 2048 + j] = s * SCALE_LOG2E;
}

// brk[h][t] padded to 2304 per h (zeros past 2047)
__global__ __launch_bounds__(256) void brk_kernel(const __bf16* __restrict__ rk,
                                                  const float* __restrict__ r_r_bias,
                                                  float* __restrict__ brk) {
  int gid = blockIdx.x * 256 + threadIdx.x;  // 36864
  int t = gid % 2304, h = gid / 2304;
  float s = 0.f;
  if (t < 2048) {
    const __bf16* rp = rk + (size_t)t * 1024 + h * 64;
    const float* br = r_r_bias + h * 64;
#pragma unroll
    for (int o = 0; o < 8; ++o) {
      bf16x8 rv = *(const bf16x8*)(rp + o * 8);
#pragma unroll
      for (int e = 0; e < 8; ++e) s += (float)rv[e] * br[o * 8 + e];
    }
  }
  brk[(size_t)h * 2304 + t] = s * SCALE_LOG2E;
}

// ---------------- attention: 32x32 MFMA, QBLK=32/wave, KVBLK=64 ----------------
// Single barrier per step: stage(s+1) issued BEFORE compute(s), sync at end.
// K double-buffer; rk in 256-slot ring (slot = row & 255); V direct from L2.
__global__ __launch_bounds__(256, 2) void attn_kernel(
    const __bf16* __restrict__ heads, const __bf16* __restrict__ rk,
    const __bf16* __restrict__ vT, const float* __restrict__ ackb,
    const float* __restrict__ brk, __bf16* __restrict__ vec) {
  __shared__ __bf16 Ks[2 * 4096];    // 16 KB K dbuf [j][d] swizzled
  __shared__ __bf16 Ring[256 * 64];  // 32 KB rk ring [slot][d] swizzled
  __shared__ __bf16 BP[4][3200];     // 25.6 KB per-wave band(100)/P(88) union

  // balanced XCD-chunked decode
  const int lin = blockIdx.x;
  const int xcd = lin & 7, s = lin >> 3;  // 512 = 8 XCD * 64
  const int half = s >> 5, r5 = s & 31;
  const int bh = xcd * 8 + (r5 >> 3) + half * 4;
  const int bqr = r5 & 7;
  const int bq = half ? bqr : 7 - bqr;
  const int b = bh >> 4, h = bh & 15;
  const int base = bq << 7;  // 128 q-rows per block

  const int tid = threadIdx.x;
  const int wid = tid >> 6, lane = tid & 63;
  const int il = lane & 31, hi5 = lane >> 5;
  const int i0 = base + wid * 32;

  const int srow8 = lane >> 3;
  const int sch = (lane & 7) ^ (srow8 & 7);

  // q fragments: lane supplies q[i0+il][ks*16 + hi5*8 + e], pre-scaled
  bf16x8 qf[4];
  {
    const __bf16* qp =
        heads + ((size_t)(b * 2048 + 1024 + i0 + il)) * 3072 + h * 64 + hi5 * 8;
#pragma unroll
    for (int ks = 0; ks < 4; ++ks) {
      bf16x8 a = *(const bf16x8*)(qp + ks * 16);
      bf16x8 o;
#pragma unroll
      for (int e = 0; e < 8; ++e) o[e] = (__bf16)((float)a[e] * SCALE_LOG2E);
      qf[ks] = o;
    }
  }

  const float* ackbp = ackb + (size_t)bh * 2048;
  const float* brkp = brk + (size_t)h * 2304;
  const __bf16* vTp = vT + (size_t)bh * 64 * 2048;
  __bf16* Bw = BP[wid];

  // ---- prologue: stage K(0) into Ks[0]; rk rows [896-base, 1088-base) ----
  {
    const __bf16* kst = heads +
        ((size_t)(b * 2048 + wid * 16 + srow8)) * 3072 + 1024 + h * 64 + sch * 8;
    gload_lds16(kst, Ks + (wid * 16) * 64);
    gload_lds16(kst + (size_t)8 * 3072, Ks + (wid * 16 + 8) * 64);
    const int rbase = 896 - base;
#pragma unroll
    for (int g = 0; g < 6; ++g) {
      const int r = rbase + wid * 48 + g * 8;  // group start, mult of 8
      const int rg = min(r + srow8, 2047);
      gload_lds16(rk + ((size_t)rg << 10) + h * 64 + sch * 8,
                  Ring + (size_t)(r & 255) * 64);
    }
  }
  __syncthreads();

  float m_run = -1e30f, l_run = 0.f;
  f32x16 accv[2] = {};

  const int jmaxb = min(2048, base + 1152);
  for (int j0 = 0; j0 < jmaxb; j0 += 64) {
    const int sbuf = (j0 >> 6) & 1;

    // ---- stage(s+1): K(j0+64) -> Ks[sbuf^1]; rk rows [j0+1088-base, +64) ----
    if (j0 + 64 < jmaxb) {
      const int jn = j0 + 64;
      const __bf16* kst = heads +
          ((size_t)(b * 2048 + jn + wid * 16 + srow8)) * 3072 + 1024 + h * 64 + sch * 8;
      gload_lds16(kst, Ks + (sbuf ^ 1) * 4096 + (wid * 16) * 64);
      gload_lds16(kst + (size_t)8 * 3072, Ks + (sbuf ^ 1) * 4096 + (wid * 16 + 8) * 64);
      const int T0 = j0 + 1088 - base;  // mult of 64
      const int r0 = T0 + wid * 16;
      gload_lds16(rk + ((size_t)min(r0 + srow8, 2047) << 10) + h * 64 + sch * 8,
                  Ring + (size_t)(r0 & 255) * 64);
      gload_lds16(rk + ((size_t)min(r0 + 8 + srow8, 2047) << 10) + h * 64 + sch * 8,
                  Ring + (size_t)((r0 + 8) & 255) * 64);
    }

    if (j0 < i0 + 1056) {  // compute(s); else fully masked for this wave
      const __bf16* KsC = Ks + sbuf * 4096;
      const int tbase = j0 + 992 - i0;  // >= 0; rk row of band col 0

      // V fragments from global (L2), issued early
      bf16x8 vfr[4][2];
#pragma unroll
      for (int jc = 0; jc < 4; ++jc)
#pragma unroll
        for (int dt = 0; dt < 2; ++dt)
          vfr[jc][dt] = *(const bf16x8*)(vTp + (size_t)(dt * 32 + il) * 2048 +
                                         j0 + jc * 16 + hi5 * 8);

      __builtin_amdgcn_s_setprio(1);
      // ---- band: rows c, cols i; C-init = brk; A = rk from Ring ----
#pragma unroll
      for (int ct = 0; ct < 3; ++ct) {
        f32x16 ci;
#pragma unroll
        for (int qd = 0; qd < 4; ++qd) {
          f32x4 b4 = *(const f32x4*)(brkp + tbase + ct * 32 + qd * 8 + hi5 * 4);
#pragma unroll
          for (int e = 0; e < 4; ++e) ci[qd * 4 + e] = b4[e];
        }
        const int slot = (tbase + ct * 32 + il) & 255;
#pragma unroll
        for (int ks = 0; ks < 4; ++ks)
          ci = mfma32(ldsfrag(Ring, slot, ks * 2 + hi5), qf[ks], ci);
#pragma unroll
        for (int qd = 0; qd < 4; ++qd) {
          union { unsigned u[2]; bf16x4 v; } pw;
          asm("v_cvt_pk_bf16_f32 %0, %1, %2"
              : "=v"(pw.u[0]) : "v"(ci[qd * 4 + 0]), "v"(ci[qd * 4 + 1]));
          asm("v_cvt_pk_bf16_f32 %0, %1, %2"
              : "=v"(pw.u[1]) : "v"(ci[qd * 4 + 2]), "v"(ci[qd * 4 + 3]));
          *(bf16x4*)(Bw + il * 100 + ct * 32 + qd * 8 + hi5 * 4) = pw.v;
        }
      }

      // ---- AC: S^T rows j, cols i; C-init = ackb; A = K from Ks ----
      f32x16 st[2];
#pragma unroll
      for (int jt = 0; jt < 2; ++jt) {
        f32x16 ci;
#pragma unroll
        for (int qd = 0; qd < 4; ++qd) {
          f32x4 a4 = *(const f32x4*)(ackbp + j0 + jt * 32 + qd * 8 + hi5 * 4);
#pragma unroll
          for (int e = 0; e < 4; ++e) ci[qd * 4 + e] = a4[e];
        }
#pragma unroll
        for (int ks = 0; ks < 4; ++ks)
          ci = mfma32(ldsfrag(KsC, jt * 32 + il, ks * 2 + hi5), qf[ks], ci);
        st[jt] = ci;
      }
      __builtin_amdgcn_s_setprio(0);

      // ---- assemble S = AC + shifted band ----
      float sv[2][16];
#pragma unroll
      for (int jt = 0; jt < 2; ++jt)
#pragma unroll
        for (int rg = 0; rg < 16; ++rg) {
          const int crow = (rg & 3) + 8 * (rg >> 2) + 4 * hi5;
          const int c = jt * 32 + crow + 31 - il;
          sv[jt][rg] = st[jt][rg] + (float)Bw[il * 100 + c];
        }
      if (j0 + 63 > i0 + 1024) {  // boundary: causal(+memlen) mask
#pragma unroll
        for (int jt = 0; jt < 2; ++jt)
#pragma unroll
          for (int rg = 0; rg < 16; ++rg) {
            const int crow = (rg & 3) + 8 * (rg >> 2) + 4 * hi5;
            if (j0 + jt * 32 + crow > i0 + il + 1024) sv[jt][rg] = -1e30f;
          }
      }

      // ---- online softmax (log2 domain), defer-rescale ----
      float mx = sv[0][0];
#pragma unroll
      for (int jt = 0; jt < 2; ++jt)
#pragma unroll
        for (int rg = 0; rg < 16; ++rg) mx = fmaxf(mx, sv[jt][rg]);
      mx = fmaxf(mx, __shfl_xor(mx, 32, 64));
      const bool resc = __any(mx > m_run + 8.0f);
      const float mn = resc ? fmaxf(m_run, mx) : m_run;
      float rs = 0.f;
#pragma unroll
      for (int jt = 0; jt < 2; ++jt)
#pragma unroll
        for (int rg = 0; rg < 16; ++rg) {
          float p = exp2f(sv[jt][rg] - mn);
          sv[jt][rg] = p;
          rs += p;
        }
      rs += __shfl_xor(rs, 32, 64);
      if (resc) {
        const float corr = exp2f(m_run - mn);
        m_run = mn;
        l_run = l_run * corr + rs;
        float c16[16];
#pragma unroll
        for (int rg = 0; rg < 16; ++rg) {
          const int crow = (rg & 3) + 8 * (rg >> 2) + 4 * hi5;
          c16[rg] = __shfl(corr, crow, 64);
        }
#pragma unroll
        for (int dt = 0; dt < 2; ++dt)
#pragma unroll
          for (int rg = 0; rg < 16; ++rg) accv[dt][rg] *= c16[rg];
      } else {
        l_run += rs;
      }

      // ---- P -> LDS [i][j] (stride 88, overwrites band region) ----
#pragma unroll
      for (int jt = 0; jt < 2; ++jt)
#pragma unroll
        for (int qd = 0; qd < 4; ++qd) {
          union { unsigned u[2]; bf16x4 v; } pw;
          asm("v_cvt_pk_bf16_f32 %0, %1, %2"
              : "=v"(pw.u[0]) : "v"(sv[jt][qd * 4 + 0]), "v"(sv[jt][qd * 4 + 1]));
          asm("v_cvt_pk_bf16_f32 %0, %1, %2"
              : "=v"(pw.u[1]) : "v"(sv[jt][qd * 4 + 2]), "v"(sv[jt][qd * 4 + 3]));
          *(bf16x4*)(Bw + il * 88 + jt * 32 + qd * 8 + hi5 * 4) = pw.v;
        }

      // ---- PV ----
      __builtin_amdgcn_s_setprio(1);
#pragma unroll
      for (int jc = 0; jc < 4; ++jc) {
        bf16x8 ap = *(const bf16x8*)(Bw + il * 88 + jc * 16 + hi5 * 8);
#pragma unroll
        for (int dt = 0; dt < 2; ++dt)
          accv[dt] = mfma32(ap, vfr[jc][dt], accv[dt]);
      }
      __builtin_amdgcn_s_setprio(0);
    }

    __syncthreads();  // single barrier: all waves done compute(s); stage(s+1) drained
  }

  // ---- epilogue ----
  float linv[16];
#pragma unroll
  for (int rg = 0; rg < 16; ++rg) {
    const int crow = (rg & 3) + 8 * (rg >> 2) + 4 * hi5;
    linv[rg] = 1.0f / __shfl(l_run, crow, 64);
  }
#pragma unroll
  for (int dt = 0; dt < 2; ++dt)
#pragma unroll
    for (int rg = 0; rg < 16; ++rg) {
      const int crow = (rg & 3) + 8 * (rg >> 2) + 4 * hi5;
      vec[((size_t)(b * 1024 + i0 + crow)) * 1024 + h * 64 + dt * 32 + il] =
          (__bf16)(accv[dt][rg] * linv[rg]);
    }
}

// ---------------- layernorm ----------------
__global__ __launch_bounds__(256) void ln_kernel(const float* __restrict__ pre,
                                                 const float* __restrict__ gamma,
                                                 const float* __restrict__ beta,
                                                 float* __restrict__ out) {
  const int row = blockIdx.x;
  const int tid = threadIdx.x;
  const float4 v = ((const float4*)(pre + (size_t)row * 1024))[tid];
  float s = v.x + v.y + v.z + v.w;
  float s2 = v.x * v.x + v.y * v.y + v.z * v.z + v.w * v.w;
#pragma unroll
  for (int off = 1; off < 64; off <<= 1) {
    s += __shfl_xor(s, off, 64);
    s2 += __shfl_xor(s2, off, 64);
  }
  __shared__ float red[8];
  const int wid = tid >> 6;
  if ((tid & 63) == 0) { red[wid * 2] = s; red[wid * 2 + 1] = s2; }
  __syncthreads();
  s = red[0] + red[2] + red[4] + red[6];
  s2 = red[1] + red[3] + red[5] + red[7];
  float mu = s * (1.0f / 1024.0f);
  float var = s2 * (1.0f / 1024.0f) - mu * mu;
  float rstd = rsqrtf(var + 1e-5f);
  float4 g = ((const float4*)gamma)[tid];
  float4 be = ((const float4*)beta)[tid];
  float4 o;
  o.x = (v.x - mu) * rstd * g.x + be.x;
  o.y = (v.y - mu) * rstd * g.y + be.y;
  o.z = (v.z - mu) * rstd * g.z + be.z;
  o.w = (v.w - mu) * rstd * g.w + be.w;
  ((float4*)(out + (size_t)row * 1024))[tid] = o;
}

// ---------------- launcher ----------------
extern "C" void kernel_launch(void* const* d_in, const int* in_sizes, int n_in,
                              void* d_out, int out_size, void* d_ws, size_t ws_size,
                              hipStream_t stream) {
  const float* w = (const float*)d_in[0];
  const float* r = (const float*)d_in[1];
  const float* mem = (const float*)d_in[2];
  const float* qkv_w = (const float*)d_in[4];
  const float* r_w = (const float*)d_in[5];
  const float* o_w = (const float*)d_in[6];
  const float* r_r_bias = (const float*)d_in[7];
  const float* r_w_bias = (const float*)d_in[8];
  const float* gamma = (const float*)d_in[9];
  const float* beta = (const float*)d_in[10];
  float* out = (float*)d_out;

  char* ws = (char*)d_ws;
  const size_t MB = 1024 * 1024;
  __bf16* catB = (__bf16*)(ws + 0);
  __bf16* vT = (__bf16*)(ws + 0);        // reuses catB region after GEMM1
  float* pre = (float*)(ws + 0);
  __bf16* qkvwB = (__bf16*)(ws + 16 * MB);
  __bf16* rB = (__bf16*)(ws + 22 * MB);
  __bf16* rwB = (__bf16*)(ws + 26 * MB);
  __bf16* owB = (__bf16*)(ws + 28 * MB);
  __bf16* headsB = (__bf16*)(ws + 30 * MB);  // 48 MB
  __bf16* rkB = (__bf16*)(ws + 78 * MB);     // 4 MB
  __bf16* vecB = (__bf16*)(ws + 82 * MB);    // 8 MB
  float* ackbF = (float*)(ws + 90 * MB);     // 512 KB
  float* brkF = (float*)(ws + 91 * MB);      // 144 KB

  cast_cat<<<4096, 256, 0, stream>>>(mem, w, catB);
  cast_plain<<<1536, 256, 0, stream>>>(qkv_w, qkvwB);
  cast_plain<<<1024, 256, 0, stream>>>(r, rB);
  cast_plain<<<512, 256, 0, stream>>>(r_w, rwB);
  cast_plain<<<512, 256, 0, stream>>>(o_w, owB);

  gemm_bt<0><<<dim3(24, 64), 256, 0, stream>>>(catB, qkvwB, headsB, nullptr, nullptr,
                                               8192, 3072, 1024, 1);
  gemm_bt<0><<<dim3(8, 16), 256, 0, stream>>>(rB, rwB, rkB, nullptr, nullptr,
                                              2048, 1024, 1024, 0);

  vtrans_kernel<<<dim3(32, 16, 4), 256, 0, stream>>>(headsB, vT);
  ackb_kernel<<<512, 256, 0, stream>>>(headsB, r_w_bias, ackbF);
  brk_kernel<<<144, 256, 0, stream>>>(rkB, r_r_bias, brkF);

  attn_kernel<<<512, 256, 0, stream>>>(headsB, rkB, vT, ackbF, brkF, vecB);

  gemm_bt<1><<<dim3(8, 32), 256, 0, stream>>>(vecB, owB, nullptr, pre, w,
                                              4096, 1024, 1024, 0);
  ln_kernel<<<4096, 256, 0, stream>>>(pre, gamma, beta, out);
}

// Round 10
// 319.158 us; speedup vs baseline: 1.0169x; 1.0169x over previous
//
#include <hip/hip_runtime.h>

typedef __attribute__((ext_vector_type(8))) __bf16 bf16x8;
typedef __attribute__((ext_vector_type(4))) __bf16 bf16x4;
typedef __attribute__((ext_vector_type(4))) float f32x4;
typedef __attribute__((ext_vector_type(16))) float f32x16;

#define SCALE_LOG2E 0.18033688011112042f  // 0.125 * log2(e)

__device__ __forceinline__ f32x4 mfma16(bf16x8 a, bf16x8 b, f32x4 c) {
  return __builtin_amdgcn_mfma_f32_16x16x32_bf16(a, b, c, 0, 0, 0);
}
__device__ __forceinline__ f32x16 mfma32(bf16x8 a, bf16x8 b, f32x16 c) {
  return __builtin_amdgcn_mfma_f32_32x32x16_bf16(a, b, c, 0, 0, 0);
}

__device__ __forceinline__ void gload_lds16(const void* g, void* l) {
  __builtin_amdgcn_global_load_lds(
      (__attribute__((address_space(1))) void*)(void*)g,
      (__attribute__((address_space(3))) void*)l, 16, 0, 0);
}

// read swizzled [row][64-elem] LDS tile: logical chunk lc (0..7) of row
__device__ __forceinline__ bf16x8 ldsfrag(const __bf16* base, int row, int lc) {
  return *(const bf16x8*)(base + row * 64 + ((lc ^ (row & 7)) << 3));
}

// ---------------- cast kernels ----------------

__global__ __launch_bounds__(256) void cast_plain(const float* __restrict__ in,
                                                  __bf16* __restrict__ out) {
  size_t t = (size_t)blockIdx.x * 256 + threadIdx.x;
  const float4* p = (const float4*)(in + t * 8);
  float4 a = p[0], b = p[1];
  bf16x8 v;
  v[0] = (__bf16)a.x; v[1] = (__bf16)a.y; v[2] = (__bf16)a.z; v[3] = (__bf16)a.w;
  v[4] = (__bf16)b.x; v[5] = (__bf16)b.y; v[6] = (__bf16)b.z; v[7] = (__bf16)b.w;
  *(bf16x8*)(out + t * 8) = v;
}

__global__ __launch_bounds__(256) void cast_cat(const float* __restrict__ mem,
                                                const float* __restrict__ w,
                                                __bf16* __restrict__ out) {
  size_t t = (size_t)blockIdx.x * 256 + threadIdx.x;
  size_t o = t * 8;
  int c = (int)(o & 1023);
  int row = (int)(o >> 10);
  int tt = row & 2047;
  int b = row >> 11;
  const float* src = (tt < 1024)
      ? (mem + ((size_t)(b * 1024 + tt) * 1024 + c))
      : (w + ((size_t)(b * 1024 + (tt - 1024)) * 1024 + c));
  float4 a = ((const float4*)src)[0], d = ((const float4*)src)[1];
  bf16x8 v;
  v[0] = (__bf16)a.x; v[1] = (__bf16)a.y; v[2] = (__bf16)a.z; v[3] = (__bf16)a.w;
  v[4] = (__bf16)d.x; v[5] = (__bf16)d.y; v[6] = (__bf16)d.z; v[7] = (__bf16)d.w;
  *(bf16x8*)(out + o) = v;
}

// ---------------- GEMM: C = A(MxK) * B(NxK)^T ----------------
// MODE 0: bf16 out (ldC). MODE 1: f32 out + residual. MODE 3: qkv fused —
//   cols < 2048 -> Cb[row*ldC+col]; cols >= 2048 -> transposed bf16 store to vTout.
template <int MODE>
__global__ __launch_bounds__(256, 2) void gemm_bt(const __bf16* __restrict__ A,
                                                  const __bf16* __restrict__ B,
                                                  __bf16* __restrict__ Cb,
                                                  float* __restrict__ Cf,
                                                  const float* __restrict__ Res,
                                                  __bf16* __restrict__ vTout,
                                                  int M, int N, int K, int ldC,
                                                  int skipq) {
  if (skipq && blockIdx.x < 8 && (blockIdx.y & 15) < 8) return;
  __shared__ __bf16 As[128 * 32];
  __shared__ __bf16 Bs[128 * 32];
  const int tid = threadIdx.x;
  const int wid = tid >> 6, lane = tid & 63;
  const int l15 = lane & 15, lhi = lane >> 4;
  const int wr = wid >> 1, wc = wid & 1;
  const size_t arow0 = (size_t)blockIdx.y * 128;
  const size_t brow0 = (size_t)blockIdx.x * 128;

  f32x4 acc[4][4] = {};

  const int c0 = tid, c1 = tid + 256;
  const int r0 = c0 >> 2, o0 = (c0 & 3) * 8;
  const int r1 = c1 >> 2, o1 = (c1 & 3) * 8;
  const __bf16* ga0 = A + (arow0 + r0) * K + o0;
  const __bf16* ga1 = A + (arow0 + r1) * K + o1;
  const __bf16* gb0 = B + (brow0 + r0) * K + o0;
  const __bf16* gb1 = B + (brow0 + r1) * K + o1;
  __bf16* la0 = As + wid * 512;
  __bf16* la1 = As + 2048 + wid * 512;
  __bf16* lb0 = Bs + wid * 512;
  __bf16* lb1 = Bs + 2048 + wid * 512;

  for (int k0 = 0; k0 < K; k0 += 32) {
    gload_lds16(ga0 + k0, la0);
    gload_lds16(ga1 + k0, la1);
    gload_lds16(gb0 + k0, lb0);
    gload_lds16(gb1 + k0, lb1);
    __syncthreads();
    bf16x8 af[4], bf[4];
#pragma unroll
    for (int m = 0; m < 4; ++m)
      af[m] = *(const bf16x8*)(As + (wr * 64 + m * 16 + l15) * 32 + lhi * 8);
#pragma unroll
    for (int n = 0; n < 4; ++n)
      bf[n] = *(const bf16x8*)(Bs + (wc * 64 + n * 16 + l15) * 32 + lhi * 8);
#pragma unroll
    for (int m = 0; m < 4; ++m)
#pragma unroll
      for (int n = 0; n < 4; ++n)
        acc[m][n] = mfma16(af[m], bf[n], acc[m][n]);
    __syncthreads();
  }

  if (MODE == 3 && brow0 >= 2048) {
    // V section: write transposed into vT[(b*1024 + colv)][j], 4 j's per store
#pragma unroll
    for (int m = 0; m < 4; ++m)
#pragma unroll
      for (int n = 0; n < 4; ++n) {
        size_t row = arow0 + wr * 64 + m * 16 + lhi * 4;  // b*2048 + j
        int colv = (int)(brow0 - 2048) + wc * 64 + n * 16 + l15;  // h*64+d
        int bb = (int)(row >> 11), j = (int)(row & 2047);
        bf16x4 pv;
        pv[0] = (__bf16)acc[m][n][0]; pv[1] = (__bf16)acc[m][n][1];
        pv[2] = (__bf16)acc[m][n][2]; pv[3] = (__bf16)acc[m][n][3];
        *(bf16x4*)(vTout + (((size_t)((bb << 10) + colv)) << 11) + j) = pv;
      }
    return;
  }

#pragma unroll
  for (int m = 0; m < 4; ++m)
#pragma unroll
    for (int n = 0; n < 4; ++n) {
      size_t row = arow0 + wr * 64 + m * 16 + lhi * 4;
      size_t col = brow0 + wc * 64 + n * 16 + l15;
#pragma unroll
      for (int j = 0; j < 4; ++j) {
        size_t idx = (row + j) * (size_t)ldC + col;
        float v = acc[m][n][j];
        if (MODE == 1) Cf[idx] = v + Res[idx];
        else Cb[idx] = (__bf16)v;
      }
    }
}

// ---------------- bias-dot precomputes (scale = 0.125*log2e folded in) ----------------
// heads layout: [8192][2048] (Q|K)
__global__ __launch_bounds__(256) void ackb_kernel(const __bf16* __restrict__ heads,
                                                   const float* __restrict__ r_w_bias,
                                                   float* __restrict__ ackb) {
  int gid = blockIdx.x * 256 + threadIdx.x;  // 131072
  int j = gid & 2047, bh = gid >> 11, b = bh >> 4, h = bh & 15;
  const __bf16* kp = heads + ((size_t)(b * 2048 + j)) * 2048 + 1024 + h * 64;
  const float* bw = r_w_bias + h * 64;
  float s = 0.f;
#pragma unroll
  for (int o = 0; o < 8; ++o) {
    bf16x8 kv = *(const bf16x8*)(kp + o * 8);
#pragma unroll
    for (int e = 0; e < 8; ++e) s += (float)kv[e] * bw[o * 8 + e];
  }
  ackb[(size_t)bh * 2048 + j] = s * SCALE_LOG2E;
}

// brk[h][t] padded to 2304 per h (zeros past 2047)
__global__ __launch_bounds__(256) void brk_kernel(const __bf16* __restrict__ rk,
                                                  const float* __restrict__ r_r_bias,
                                                  float* __restrict__ brk) {
  int gid = blockIdx.x * 256 + threadIdx.x;  // 36864
  int t = gid % 2304, h = gid / 2304;
  float s = 0.f;
  if (t < 2048) {
    const __bf16* rp = rk + (size_t)t * 1024 + h * 64;
    const float* br = r_r_bias + h * 64;
#pragma unroll
    for (int o = 0; o < 8; ++o) {
      bf16x8 rv = *(const bf16x8*)(rp + o * 8);
#pragma unroll
      for (int e = 0; e < 8; ++e) s += (float)rv[e] * br[o * 8 + e];
    }
  }
  brk[(size_t)h * 2304 + t] = s * SCALE_LOG2E;
}

// ---------------- attention: 32x32 MFMA, QBLK=32/wave, KVBLK=64 ----------------
// R7-proven structure: K double-buffer LDS; rk 256-slot ring (min size for
// stage-during-compute: evicted rows [j0+832,j0+896) are below all readers).
// Single barrier per step (stage(s+1) before compute(s)). heads ld = 2048.
__global__ __launch_bounds__(256, 2) void attn_kernel(
    const __bf16* __restrict__ heads, const __bf16* __restrict__ rk,
    const __bf16* __restrict__ vT, const float* __restrict__ ackb,
    const float* __restrict__ brk, __bf16* __restrict__ vec) {
  __shared__ __bf16 Ks[2 * 4096];    // 16 KB K dbuf [j][d] swizzled
  __shared__ __bf16 Ring[256 * 64];  // 32 KB rk ring [slot][d] swizzled
  __shared__ __bf16 BP[4][3200];     // 25.6 KB per-wave band(100)/P(88) union

  // balanced XCD-chunked decode
  const int lin = blockIdx.x;
  const int xcd = lin & 7, s = lin >> 3;  // 512 = 8 XCD * 64
  const int half = s >> 5, r5 = s & 31;
  const int bh = xcd * 8 + (r5 >> 3) + half * 4;
  const int bqr = r5 & 7;
  const int bq = half ? bqr : 7 - bqr;
  const int b = bh >> 4, h = bh & 15;
  const int base = bq << 7;  // 128 q-rows per block

  const int tid = threadIdx.x;
  const int wid = tid >> 6, lane = tid & 63;
  const int il = lane & 31, hi5 = lane >> 5;
  const int i0 = base + wid * 32;

  const int srow8 = lane >> 3;
  const int sch = (lane & 7) ^ (srow8 & 7);

  // q fragments: lane supplies q[i0+il][ks*16 + hi5*8 + e], pre-scaled
  bf16x8 qf[4];
  {
    const __bf16* qp =
        heads + ((size_t)(b * 2048 + 1024 + i0 + il)) * 2048 + h * 64 + hi5 * 8;
#pragma unroll
    for (int ks = 0; ks < 4; ++ks) {
      bf16x8 a = *(const bf16x8*)(qp + ks * 16);
      bf16x8 o;
#pragma unroll
      for (int e = 0; e < 8; ++e) o[e] = (__bf16)((float)a[e] * SCALE_LOG2E);
      qf[ks] = o;
    }
  }

  const float* ackbp = ackb + (size_t)bh * 2048;
  const float* brkp = brk + (size_t)h * 2304;
  const __bf16* vTp = vT + (size_t)bh * 64 * 2048;
  __bf16* Bw = BP[wid];

  // ---- prologue: stage K(0) into Ks[0]; rk rows [896-base, 1088-base) ----
  {
    const __bf16* kst = heads +
        ((size_t)(b * 2048 + wid * 16 + srow8)) * 2048 + 1024 + h * 64 + sch * 8;
    gload_lds16(kst, Ks + (wid * 16) * 64);
    gload_lds16(kst + (size_t)8 * 2048, Ks + (wid * 16 + 8) * 64);
    const int rbase = 896 - base;
#pragma unroll
    for (int g = 0; g < 6; ++g) {
      const int r = rbase + wid * 48 + g * 8;  // group start, mult of 8
      const int rg = min(r + srow8, 2047);
      gload_lds16(rk + ((size_t)rg << 10) + h * 64 + sch * 8,
                  Ring + (size_t)(r & 255) * 64);
    }
  }
  __syncthreads();

  float m_run = -1e30f, l_run = 0.f;
  f32x16 accv[2] = {};

  const int jmaxb = min(2048, base + 1152);
  for (int j0 = 0; j0 < jmaxb; j0 += 64) {
    const int sbuf = (j0 >> 6) & 1;

    // ---- stage(s+1): K(j0+64) -> Ks[sbuf^1]; rk rows [j0+1088-base, +64) ----
    if (j0 + 64 < jmaxb) {
      const int jn = j0 + 64;
      const __bf16* kst = heads +
          ((size_t)(b * 2048 + jn + wid * 16 + srow8)) * 2048 + 1024 + h * 64 + sch * 8;
      gload_lds16(kst, Ks + (sbuf ^ 1) * 4096 + (wid * 16) * 64);
      gload_lds16(kst + (size_t)8 * 2048, Ks + (sbuf ^ 1) * 4096 + (wid * 16 + 8) * 64);
      const int T0 = j0 + 1088 - base;  // mult of 64
      const int r0 = T0 + wid * 16;
      gload_lds16(rk + ((size_t)min(r0 + srow8, 2047) << 10) + h * 64 + sch * 8,
                  Ring + (size_t)(r0 & 255) * 64);
      gload_lds16(rk + ((size_t)min(r0 + 8 + srow8, 2047) << 10) + h * 64 + sch * 8,
                  Ring + (size_t)((r0 + 8) & 255) * 64);
    }

    if (j0 < i0 + 1056) {  // compute(s); else fully masked for this wave
      const __bf16* KsC = Ks + sbuf * 4096;
      const int tbase = j0 + 992 - i0;  // >= 0; rk row of band col 0

      // V fragments from global (L2), issued early
      bf16x8 vfr[4][2];
#pragma unroll
      for (int jc = 0; jc < 4; ++jc)
#pragma unroll
        for (int dt = 0; dt < 2; ++dt)
          vfr[jc][dt] = *(const bf16x8*)(vTp + (size_t)(dt * 32 + il) * 2048 +
                                         j0 + jc * 16 + hi5 * 8);

      __builtin_amdgcn_s_setprio(1);
      // ---- band: rows c, cols i; C-init = brk; A = rk from Ring ----
#pragma unroll
      for (int ct = 0; ct < 3; ++ct) {
        f32x16 ci;
#pragma unroll
        for (int qd = 0; qd < 4; ++qd) {
          f32x4 b4 = *(const f32x4*)(brkp + tbase + ct * 32 + qd * 8 + hi5 * 4);
#pragma unroll
          for (int e = 0; e < 4; ++e) ci[qd * 4 + e] = b4[e];
        }
        const int slot = (tbase + ct * 32 + il) & 255;
#pragma unroll
        for (int ks = 0; ks < 4; ++ks)
          ci = mfma32(ldsfrag(Ring, slot, ks * 2 + hi5), qf[ks], ci);
#pragma unroll
        for (int qd = 0; qd < 4; ++qd) {
          union { unsigned u[2]; bf16x4 v; } pw;
          asm("v_cvt_pk_bf16_f32 %0, %1, %2"
              : "=v"(pw.u[0]) : "v"(ci[qd * 4 + 0]), "v"(ci[qd * 4 + 1]));
          asm("v_cvt_pk_bf16_f32 %0, %1, %2"
              : "=v"(pw.u[1]) : "v"(ci[qd * 4 + 2]), "v"(ci[qd * 4 + 3]));
          *(bf16x4*)(Bw + il * 100 + ct * 32 + qd * 8 + hi5 * 4) = pw.v;
        }
      }

      // ---- AC: S^T rows j, cols i; C-init = ackb; A = K from Ks ----
      f32x16 st[2];
#pragma unroll
      for (int jt = 0; jt < 2; ++jt) {
        f32x16 ci;
#pragma unroll
        for (int qd = 0; qd < 4; ++qd) {
          f32x4 a4 = *(const f32x4*)(ackbp + j0 + jt * 32 + qd * 8 + hi5 * 4);
#pragma unroll
          for (int e = 0; e < 4; ++e) ci[qd * 4 + e] = a4[e];
        }
#pragma unroll
        for (int ks = 0; ks < 4; ++ks)
          ci = mfma32(ldsfrag(KsC, jt * 32 + il, ks * 2 + hi5), qf[ks], ci);
        st[jt] = ci;
      }
      __builtin_amdgcn_s_setprio(0);

      // ---- assemble S = AC + shifted band ----
      float sv[2][16];
#pragma unroll
      for (int jt = 0; jt < 2; ++jt)
#pragma unroll
        for (int rg = 0; rg < 16; ++rg) {
          const int crow = (rg & 3) + 8 * (rg >> 2) + 4 * hi5;
          const int c = jt * 32 + crow + 31 - il;
          sv[jt][rg] = st[jt][rg] + (float)Bw[il * 100 + c];
        }
      if (j0 + 63 > i0 + 1024) {  // boundary: causal(+memlen) mask
#pragma unroll
        for (int jt = 0; jt < 2; ++jt)
#pragma unroll
          for (int rg = 0; rg < 16; ++rg) {
            const int crow = (rg & 3) + 8 * (rg >> 2) + 4 * hi5;
            if (j0 + jt * 32 + crow > i0 + il + 1024) sv[jt][rg] = -1e30f;
          }
      }

      // ---- online softmax (log2 domain), defer-rescale ----
      float mx = sv[0][0];
#pragma unroll
      for (int jt = 0; jt < 2; ++jt)
#pragma unroll
        for (int rg = 0; rg < 16; ++rg) mx = fmaxf(mx, sv[jt][rg]);
      mx = fmaxf(mx, __shfl_xor(mx, 32, 64));
      const bool resc = __any(mx > m_run + 8.0f);
      const float mn = resc ? fmaxf(m_run, mx) : m_run;
      float rs = 0.f;
#pragma unroll
      for (int jt = 0; jt < 2; ++jt)
#pragma unroll
        for (int rg = 0; rg < 16; ++rg) {
          float p = exp2f(sv[jt][rg] - mn);
          sv[jt][rg] = p;
          rs += p;
        }
      rs += __shfl_xor(rs, 32, 64);
      if (resc) {
        const float corr = exp2f(m_run - mn);
        m_run = mn;
        l_run = l_run * corr + rs;
        float c16[16];
#pragma unroll
        for (int rg = 0; rg < 16; ++rg) {
          const int crow = (rg & 3) + 8 * (rg >> 2) + 4 * hi5;
          c16[rg] = __shfl(corr, crow, 64);
        }
#pragma unroll
        for (int dt = 0; dt < 2; ++dt)
#pragma unroll
          for (int rg = 0; rg < 16; ++rg) accv[dt][rg] *= c16[rg];
      } else {
        l_run += rs;
      }

      // ---- P -> LDS [i][j] (stride 88, overwrites band region) ----
#pragma unroll
      for (int jt = 0; jt < 2; ++jt)
#pragma unroll
        for (int qd = 0; qd < 4; ++qd) {
          union { unsigned u[2]; bf16x4 v; } pw;
          asm("v_cvt_pk_bf16_f32 %0, %1, %2"
              : "=v"(pw.u[0]) : "v"(sv[jt][qd * 4 + 0]), "v"(sv[jt][qd * 4 + 1]));
          asm("v_cvt_pk_bf16_f32 %0, %1, %2"
              : "=v"(pw.u[1]) : "v"(sv[jt][qd * 4 + 2]), "v"(sv[jt][qd * 4 + 3]));
          *(bf16x4*)(Bw + il * 88 + jt * 32 + qd * 8 + hi5 * 4) = pw.v;
        }

      // ---- PV ----
      __builtin_amdgcn_s_setprio(1);
#pragma unroll
      for (int jc = 0; jc < 4; ++jc) {
        bf16x8 ap = *(const bf16x8*)(Bw + il * 88 + jc * 16 + hi5 * 8);
#pragma unroll
        for (int dt = 0; dt < 2; ++dt)
          accv[dt] = mfma32(ap, vfr[jc][dt], accv[dt]);
      }
      __builtin_amdgcn_s_setprio(0);
    }

    __syncthreads();  // all waves done compute(s); stage(s+1) drained
  }

  // ---- epilogue ----
  float linv[16];
#pragma unroll
  for (int rg = 0; rg < 16; ++rg) {
    const int crow = (rg & 3) + 8 * (rg >> 2) + 4 * hi5;
    linv[rg] = 1.0f / __shfl(l_run, crow, 64);
  }
#pragma unroll
  for (int dt = 0; dt < 2; ++dt)
#pragma unroll
    for (int rg = 0; rg < 16; ++rg) {
      const int crow = (rg & 3) + 8 * (rg >> 2) + 4 * hi5;
      vec[((size_t)(b * 1024 + i0 + crow)) * 1024 + h * 64 + dt * 32 + il] =
          (__bf16)(accv[dt][rg] * linv[rg]);
    }
}

// ---------------- layernorm ----------------
__global__ __launch_bounds__(256) void ln_kernel(const float* __restrict__ pre,
                                                 const float* __restrict__ gamma,
                                                 const float* __restrict__ beta,
                                                 float* __restrict__ out) {
  const int row = blockIdx.x;
  const int tid = threadIdx.x;
  const float4 v = ((const float4*)(pre + (size_t)row * 1024))[tid];
  float s = v.x + v.y + v.z + v.w;
  float s2 = v.x * v.x + v.y * v.y + v.z * v.z + v.w * v.w;
#pragma unroll
  for (int off = 1; off < 64; off <<= 1) {
    s += __shfl_xor(s, off, 64);
    s2 += __shfl_xor(s2, off, 64);
  }
  __shared__ float red[8];
  const int wid = tid >> 6;
  if ((tid & 63) == 0) { red[wid * 2] = s; red[wid * 2 + 1] = s2; }
  __syncthreads();
  s = red[0] + red[2] + red[4] + red[6];
  s2 = red[1] + red[3] + red[5] + red[7];
  float mu = s * (1.0f / 1024.0f);
  float var = s2 * (1.0f / 1024.0f) - mu * mu;
  float rstd = rsqrtf(var + 1e-5f);
  float4 g = ((const float4*)gamma)[tid];
  float4 be = ((const float4*)beta)[tid];
  float4 o;
  o.x = (v.x - mu) * rstd * g.x + be.x;
  o.y = (v.y - mu) * rstd * g.y + be.y;
  o.z = (v.z - mu) * rstd * g.z + be.z;
  o.w = (v.w - mu) * rstd * g.w + be.w;
  ((float4*)(out + (size_t)row * 1024))[tid] = o;
}

// ---------------- launcher ----------------
extern "C" void kernel_launch(void* const* d_in, const int* in_sizes, int n_in,
                              void* d_out, int out_size, void* d_ws, size_t ws_size,
                              hipStream_t stream) {
  const float* w = (const float*)d_in[0];
  const float* r = (const float*)d_in[1];
  const float* mem = (const float*)d_in[2];
  const float* qkv_w = (const float*)d_in[4];
  const float* r_w = (const float*)d_in[5];
  const float* o_w = (const float*)d_in[6];
  const float* r_r_bias = (const float*)d_in[7];
  const float* r_w_bias = (const float*)d_in[8];
  const float* gamma = (const float*)d_in[9];
  const float* beta = (const float*)d_in[10];
  float* out = (float*)d_out;

  char* ws = (char*)d_ws;
  const size_t MB = 1024 * 1024;
  __bf16* catB = (__bf16*)(ws + 0);          // 16 MB (pre overlays later)
  float* pre = (float*)(ws + 0);
  __bf16* qkvwB = (__bf16*)(ws + 16 * MB);   // 6 MB
  __bf16* rB = (__bf16*)(ws + 22 * MB);      // 4 MB
  __bf16* rwB = (__bf16*)(ws + 26 * MB);     // 2 MB
  __bf16* owB = (__bf16*)(ws + 28 * MB);     // 2 MB
  __bf16* headsB = (__bf16*)(ws + 30 * MB);  // 32 MB [8192][2048] Q|K
  __bf16* vT = (__bf16*)(ws + 62 * MB);      // 16 MB [(b*16+h)*64+d][2048]
  __bf16* rkB = (__bf16*)(ws + 78 * MB);     // 4 MB
  __bf16* vecB = (__bf16*)(ws + 82 * MB);    // 8 MB
  float* ackbF = (float*)(ws + 90 * MB);     // 512 KB
  float* brkF = (float*)(ws + 91 * MB);      // 144 KB

  cast_cat<<<4096, 256, 0, stream>>>(mem, w, catB);
  cast_plain<<<1536, 256, 0, stream>>>(qkv_w, qkvwB);
  cast_plain<<<1024, 256, 0, stream>>>(r, rB);
  cast_plain<<<512, 256, 0, stream>>>(r_w, rwB);
  cast_plain<<<512, 256, 0, stream>>>(o_w, owB);

  // heads (Q|K -> headsB ld 2048) + V transposed -> vT, fused
  gemm_bt<3><<<dim3(24, 64), 256, 0, stream>>>(catB, qkvwB, headsB, nullptr, nullptr,
                                               vT, 8192, 3072, 1024, 2048, 1);
  gemm_bt<0><<<dim3(8, 16), 256, 0, stream>>>(rB, rwB, rkB, nullptr, nullptr, nullptr,
                                              2048, 1024, 1024, 1024, 0);

  ackb_kernel<<<512, 256, 0, stream>>>(headsB, r_w_bias, ackbF);
  brk_kernel<<<144, 256, 0, stream>>>(rkB, r_r_bias, brkF);

  attn_kernel<<<512, 256, 0, stream>>>(headsB, rkB, vT, ackbF, brkF, vecB);

  gemm_bt<1><<<dim3(8, 32), 256, 0, stream>>>(vecB, owB, nullptr, pre, w, nullptr,
                                              4096, 1024, 1024, 1024, 0);
  ln_kernel<<<4096, 256, 0, stream>>>(pre, gamma, beta, out);
}